// Round 5
// baseline (89.686 us; speedup 1.0000x reference)
//
#include <hip/hip_runtime.h>
#include <hip/hip_bf16.h>

#define NROWS 16384
#define DIM   768
#define PP    256
#define BT    64
#define EPSF  1e-6f
#define KC    32
#define LP    40   // LDS row pitch in ushorts (80 B)

typedef short          bf16x8 __attribute__((ext_vector_type(8)));
typedef float          f32x4  __attribute__((ext_vector_type(4)));
typedef unsigned short us8    __attribute__((ext_vector_type(8)));

__device__ __forceinline__ unsigned short f2bf(float x) {
    __hip_bfloat16 h = __float2bfloat16(x);
    return *reinterpret_cast<unsigned short*>(&h);
}

// ---------------------------------------------------------------- kernel 1
// Per-row inv-norms + patch_loss. Read-only over in/tg (100 MB), tiny writes.
__global__ __launch_bounds__(256) void k_norms(const float* __restrict__ in,
                                               const float* __restrict__ tg,
                                               float* __restrict__ inv_in,
                                               float* __restrict__ inv_tg,
                                               float* __restrict__ ploss) {
    int row  = blockIdx.x * 4 + (threadIdx.x >> 6);
    int lane = threadIdx.x & 63;
    const float4* ip = (const float4*)(in + (size_t)row * DIM);
    const float4* tp = (const float4*)(tg + (size_t)row * DIM);
    float si = 0.f, st = 0.f, sd = 0.f;
#pragma unroll
    for (int v = 0; v < 3; ++v) {
        float4 a = ip[lane + 64 * v], t = tp[lane + 64 * v];
        si += a.x * a.x + a.y * a.y + a.z * a.z + a.w * a.w;
        st += t.x * t.x + t.y * t.y + t.z * t.z + t.w * t.w;
        float dx = a.x - t.x, dy = a.y - t.y, dz = a.z - t.z, dw = a.w - t.w;
        sd += dx * dx + dy * dy + dz * dz + dw * dw;
    }
#pragma unroll
    for (int o = 32; o; o >>= 1) {
        si += __shfl_xor(si, o); st += __shfl_xor(st, o); sd += __shfl_xor(sd, o);
    }
    if (lane == 0) {
        inv_in[row] = 1.f / fmaxf(sqrtf(si), 1e-12f);
        inv_tg[row] = 1.f / fmaxf(sqrtf(st), 1e-12f);
        ploss[row]  = sd * (1.f / DIM);
    }
}

// ------------------------------------------- weights pipeline (all f32!)
// tf/idf denominators are near-zero means (gram row-mean ~4e-3, cross_mean
// ~6e-5) — bf16 anywhere upstream of the reciprocals flips signs (round-3
// failure). Everything feeding weights stays f32.

// stage 1: partial block sums of normalized target rows; rows split 4-way.
__global__ __launch_bounds__(64) void k_bsum1(const float* __restrict__ tg,
                                              const float* __restrict__ inv_tg,
                                              float* __restrict__ psum) {
    int b = blockIdx.x, y = blockIdx.y, h = blockIdx.z;
    int d0 = y * 256 + threadIdx.x * 4;
    const float* base = tg + (size_t)(b * PP + h * 64) * DIM + d0;
    const float* itg  = inv_tg + b * PP + h * 64;
    float4 s = { 0.f, 0.f, 0.f, 0.f };
    for (int r = 0; r < 64; ++r) {
        float4 v = *(const float4*)(base + (size_t)r * DIM);
        float w = itg[r];
        s.x += v.x * w; s.y += v.y * w; s.z += v.z * w; s.w += v.w * w;
    }
    *(float4*)(psum + (size_t)(b * 4 + h) * DIM + d0) = s;
}

// stage 2: merge quarters -> bsum[b][d]; global mean va[d].
__global__ __launch_bounds__(256) void k_bsum2(const float* __restrict__ psum,
                                               float* __restrict__ bsum,
                                               float* __restrict__ va) {
    int d = blockIdx.x * 256 + threadIdx.x;
    if (d >= DIM) return;
    float g = 0.f;
    for (int b = 0; b < BT; ++b) {
        float s = psum[(size_t)(b * 4 + 0) * DIM + d] + psum[(size_t)(b * 4 + 1) * DIM + d]
                + psum[(size_t)(b * 4 + 2) * DIM + d] + psum[(size_t)(b * 4 + 3) * DIM + d];
        bsum[b * DIM + d] = s;
        g += s;
    }
    va[d] = g * (1.f / NROWS);
}

// wave-per-row raw weights: w = 1/(db/P+eps) * 1/(da+eps)
__global__ __launch_bounds__(256) void k_wdots(const float* __restrict__ tg,
                                               const float* __restrict__ inv_tg,
                                               const float* __restrict__ bsum,
                                               const float* __restrict__ va,
                                               float* __restrict__ wraw) {
    int wave = threadIdx.x >> 6, lane = threadIdx.x & 63;
    int gw = blockIdx.x * 4 + wave;
#pragma unroll
    for (int rr = 0; rr < 4; ++rr) {
        int row = gw * 4 + rr;
        int b   = row >> 8;
        const float4* t4 = (const float4*)(tg + (size_t)row * DIM);
        const float4* b4 = (const float4*)(bsum + b * DIM);
        const float4* a4 = (const float4*)va;
        float db = 0.f, da = 0.f;
#pragma unroll
        for (int v = 0; v < 3; ++v) {
            float4 t = t4[lane + 64 * v];
            float4 x = b4[lane + 64 * v];
            float4 y = a4[lane + 64 * v];
            db += t.x * x.x + t.y * x.y + t.z * x.z + t.w * x.w;
            da += t.x * y.x + t.y * y.y + t.z * y.z + t.w * y.w;
        }
#pragma unroll
        for (int o = 32; o; o >>= 1) { db += __shfl_xor(db, o); da += __shfl_xor(da, o); }
        if (lane == 0) {
            float itg = inv_tg[row];
            db *= itg; da *= itg;
            wraw[row] = (1.f / (db * (1.f / PP) + EPSF)) * (1.f / (da + EPSF));
        }
    }
}

// normalize weights (deterministic per-block sum) + sim loss partial per block
__global__ __launch_bounds__(256) void k_wfinal(const float* __restrict__ wraw,
                                                const float* __restrict__ ploss,
                                                float* __restrict__ weights,
                                                float* __restrict__ simpart) {
    __shared__ float red[256];
    int b = blockIdx.x, p = threadIdx.x, row = b * PP + p;
    float w = wraw[row];
    red[p] = w; __syncthreads();
    for (int s = 128; s; s >>= 1) { if (p < s) red[p] += red[p + s]; __syncthreads(); }
    float wn = w / (red[0] + EPSF);
    weights[row] = wn;
    __syncthreads();
    red[p] = wn * ploss[row]; __syncthreads();
    for (int s = 128; s; s >>= 1) { if (p < s) red[p] += red[p + s]; __syncthreads(); }
    if (p == 0) simpart[b] = red[0];
}

// ---------------------------------------------------------------- kernel 4
// bf16 MFMA dual-gram, staging straight from f32 inputs (L3-resident),
// converting to bf16 in STAGE_WRITE. Per-WG partial -> grampart[wg].
__global__ __launch_bounds__(256) void k_gram(const float* __restrict__ in,
                                              const float* __restrict__ tg,
                                              const float* __restrict__ inv_in,
                                              const float* __restrict__ inv_tg,
                                              const float* __restrict__ weights,
                                              float* __restrict__ grampart) {
    __shared__ __align__(16) unsigned short LA0[128 * LP];
    __shared__ __align__(16) unsigned short LA1[128 * LP];
    __shared__ __align__(16) unsigned short LB0[128 * LP];
    __shared__ __align__(16) unsigned short LB1[128 * LP];
    __shared__ float red[256];

    const int wg  = blockIdx.x;
    const int xcd = wg & 7, j = wg >> 3;          // XCD-chunked block mapping
    const int b   = xcd * 8 + j / 3;
    const int t3  = j % 3;
    const int pr  = (t3 == 2) ? 128 : 0;
    const int qc  = (t3 == 0) ? 0 : 128;
    const bool diag = (pr == qc);
    const float factor = diag ? 1.f : 2.f;

    const int tid  = threadIdx.x;
    const int lane = tid & 63;
    const int wave = tid >> 6;
    const int wr = (wave >> 1) * 64, wc = (wave & 1) * 64;
    const int bP = b * PP;

    const int strow = tid >> 2;
    const int skq   = tid & 3;
    const int sw    = (strow >> 3) & 3;

    const float* srcf[4] = { in, tg, in, tg };
    unsigned short* ldst[4] = { LA0, LA1, LB0, LB1 };

    size_t g[4][2];
#pragma unroll
    for (int h = 0; h < 2; ++h) {
        g[0][h] = (size_t)(bP + pr + strow + h * 64) * DIM + skq * 8;
        g[1][h] = g[0][h];
        g[2][h] = (size_t)(bP + qc + strow + h * 64) * DIM + skq * 8;
        g[3][h] = g[2][h];
    }
    float scl[4][2];
#pragma unroll
    for (int h = 0; h < 2; ++h) {
        scl[0][h] = inv_in[bP + pr + strow + h * 64];
        scl[1][h] = inv_tg[bP + pr + strow + h * 64];
        scl[2][h] = inv_in[bP + qc + strow + h * 64];
        scl[3][h] = inv_tg[bP + qc + strow + h * 64];
    }

    float4 pfa[4][2], pfb[4][2];

    auto STAGE_LOAD = [&](int k0) {
#pragma unroll
        for (int bi = 0; bi < 4; ++bi) {
            if (bi >= 2 && diag) continue;
#pragma unroll
            for (int h = 0; h < 2; ++h) {
                pfa[bi][h] = *(const float4*)(srcf[bi] + g[bi][h] + k0);
                pfb[bi][h] = *(const float4*)(srcf[bi] + g[bi][h] + k0 + 4);
            }
        }
    };
    auto STAGE_WRITE = [&]() {
#pragma unroll
        for (int bi = 0; bi < 4; ++bi) {
            if (bi >= 2 && diag) continue;
#pragma unroll
            for (int h = 0; h < 2; ++h) {
                us8 v;
                float s = scl[bi][h];
                float4 x = pfa[bi][h], y = pfb[bi][h];
                v[0] = f2bf(x.x * s); v[1] = f2bf(x.y * s);
                v[2] = f2bf(x.z * s); v[3] = f2bf(x.w * s);
                v[4] = f2bf(y.x * s); v[5] = f2bf(y.y * s);
                v[6] = f2bf(y.z * s); v[7] = f2bf(y.w * s);
                int row = strow + h * 64;
                *(us8*)&ldst[bi][row * LP + (skq ^ sw) * 8] = v;
            }
        }
    };

    const unsigned short* RB0 = diag ? LA0 : LB0;
    const unsigned short* RB1 = diag ? LA1 : LB1;

    f32x4 accI[4][4], accT[4][4];
#pragma unroll
    for (int m = 0; m < 4; ++m)
#pragma unroll
        for (int n = 0; n < 4; ++n) {
            f32x4 z = { 0.f, 0.f, 0.f, 0.f };
            accI[m][n] = z; accT[m][n] = z;
        }

    STAGE_LOAD(0);
    for (int ks = 0; ks < DIM / KC; ++ks) {
        __syncthreads();
        STAGE_WRITE();
        __syncthreads();
        if (ks + 1 < DIM / KC) STAGE_LOAD(KC * (ks + 1));

        bf16x8 aI[4], aT[4], bI[4], bT[4];
#pragma unroll
        for (int m = 0; m < 4; ++m) {
            int row = wr + m * 16 + (lane & 15);
            int off = row * LP + (((lane >> 4) ^ ((row >> 3) & 3))) * 8;
            aI[m] = *(const bf16x8*)&LA0[off];
            aT[m] = *(const bf16x8*)&LA1[off];
        }
#pragma unroll
        for (int n = 0; n < 4; ++n) {
            int row = wc + n * 16 + (lane & 15);
            int off = row * LP + (((lane >> 4) ^ ((row >> 3) & 3))) * 8;
            bI[n] = *(const bf16x8*)&RB0[off];
            bT[n] = *(const bf16x8*)&RB1[off];
        }
#pragma unroll
        for (int m = 0; m < 4; ++m)
#pragma unroll
            for (int n = 0; n < 4; ++n) {
                accI[m][n] = __builtin_amdgcn_mfma_f32_16x16x32_bf16(aI[m], bI[n], accI[m][n], 0, 0, 0);
                accT[m][n] = __builtin_amdgcn_mfma_f32_16x16x32_bf16(aT[m], bT[n], accT[m][n], 0, 0, 0);
            }
    }

    const int r4 = lane >> 4, cl = lane & 15;
    float wq[4], wp[4][4];
#pragma unroll
    for (int n = 0; n < 4; ++n) wq[n] = weights[bP + qc + wc + n * 16 + cl];
#pragma unroll
    for (int m = 0; m < 4; ++m)
#pragma unroll
        for (int r = 0; r < 4; ++r) wp[m][r] = weights[bP + pr + wr + m * 16 + r4 * 4 + r];
    float local = 0.f;
#pragma unroll
    for (int m = 0; m < 4; ++m)
#pragma unroll
        for (int n = 0; n < 4; ++n)
#pragma unroll
            for (int r = 0; r < 4; ++r) {
                float d = accI[m][n][r] - accT[m][n][r];
                local += wp[m][r] * wq[n] * d * d;
            }
    local *= factor;
    red[tid] = local; __syncthreads();
    for (int s = 128; s; s >>= 1) { if (tid < s) red[tid] += red[tid + s]; __syncthreads(); }
    if (tid == 0) grampart[blockIdx.x] = red[0];
}

// ---------------------------------------------------------------- kernel 5
// Final reduce of 64 sim partials + 192 gram partials (deterministic).
__global__ __launch_bounds__(256) void k_final(const float* __restrict__ simpart,
                                               const float* __restrict__ grampart,
                                               float* __restrict__ out) {
    __shared__ float red[256];
    int t = threadIdx.x;
    float v = 0.f;
    if (t < BT) v += simpart[t];
    if (t < 192) v += 10.f * grampart[t];
    red[t] = v; __syncthreads();
    for (int s = 128; s; s >>= 1) { if (t < s) red[t] += red[t + s]; __syncthreads(); }
    if (t == 0) out[0] = red[0] * (1.f / BT);
}

// ---------------------------------------------------------------- launch
extern "C" void kernel_launch(void* const* d_in, const int* in_sizes, int n_in,
                              void* d_out, int out_size, void* d_ws, size_t ws_size,
                              hipStream_t stream) {
    (void)in_sizes; (void)n_in; (void)out_size; (void)ws_size;
    const float* in = (const float*)d_in[0];
    const float* tg = (const float*)d_in[1];

    float* fbase   = (float*)d_ws;
    float* inv_in  = fbase;
    float* inv_tg  = fbase + NROWS;
    float* ploss   = fbase + 2 * (size_t)NROWS;
    float* wraw    = fbase + 3 * (size_t)NROWS;
    float* weights = fbase + 4 * (size_t)NROWS;
    float* psum    = fbase + 5 * (size_t)NROWS;            // 4*BT*DIM
    float* bsum    = psum + 4 * (size_t)BT * DIM;          // BT*DIM
    float* va      = bsum + (size_t)BT * DIM;              // DIM
    float* simpart = va + DIM;                             // BT
    float* grampart= simpart + BT;                         // 192

    k_norms<<<NROWS / 4, 256, 0, stream>>>(in, tg, inv_in, inv_tg, ploss);
    k_bsum1<<<dim3(BT, 3, 4), 64, 0, stream>>>(tg, inv_tg, psum);
    k_bsum2<<<3, 256, 0, stream>>>(psum, bsum, va);
    k_wdots<<<NROWS / 16, 256, 0, stream>>>(tg, inv_tg, bsum, va, wraw);
    k_wfinal<<<BT, 256, 0, stream>>>(wraw, ploss, weights, simpart);
    k_gram<<<192, 256, 0, stream>>>(in, tg, inv_in, inv_tg, weights, grampart);
    k_final<<<1, 256, 0, stream>>>(simpart, grampart, (float*)d_out);
}

// Round 6
// 79.136 us; speedup vs baseline: 1.1333x; 1.1333x over previous
//
#include <hip/hip_runtime.h>
#include <hip/hip_bf16.h>

#define NROWS 16384
#define DIM   768
#define PP    256
#define BT    64
#define EPSF  1e-6f
#define GKC   32     // k_gram K-chunk
#define NTILE 10     // symmetric 64x64 tile pairs per block
#define NGRAM (BT * NTILE)   // 640 WGs

typedef short          bf16x8 __attribute__((ext_vector_type(8)));
typedef float          f32x4  __attribute__((ext_vector_type(4)));
typedef unsigned short us8    __attribute__((ext_vector_type(8)));

__device__ __forceinline__ unsigned short f2bf(float x) {
    __hip_bfloat16 h = __float2bfloat16(x);
    return *reinterpret_cast<unsigned short*>(&h);
}

// ---------------------------------------------------------------- kernel 1
// Per-row inv-norms + patch_loss; PRE=1 also writes bf16 normalized copies.
// 512 threads, half-wave (32 lanes) per row, 16 rows/WG, us8 (16B) stores.
template<int PRE>
__global__ __launch_bounds__(512) void k_norms(const float* __restrict__ in,
                                               const float* __restrict__ tg,
                                               float* __restrict__ inv_in,
                                               float* __restrict__ inv_tg,
                                               float* __restrict__ ploss,
                                               unsigned short* __restrict__ in_n,
                                               unsigned short* __restrict__ tg_n) {
    const int row = blockIdx.x * 16 + (threadIdx.x >> 5);
    const int c   = threadIdx.x & 31;
    const float4* ip = (const float4*)(in + (size_t)row * DIM);
    const float4* tp = (const float4*)(tg + (size_t)row * DIM);
    float4 a[6], t[6];
#pragma unroll
    for (int k = 0; k < 3; ++k) {
        a[2*k]   = ip[2*c + 64*k];     a[2*k+1] = ip[2*c + 64*k + 1];
        t[2*k]   = tp[2*c + 64*k];     t[2*k+1] = tp[2*c + 64*k + 1];
    }
    float si = 0.f, st = 0.f, sd = 0.f;
#pragma unroll
    for (int k = 0; k < 6; ++k) {
        si += a[k].x*a[k].x + a[k].y*a[k].y + a[k].z*a[k].z + a[k].w*a[k].w;
        st += t[k].x*t[k].x + t[k].y*t[k].y + t[k].z*t[k].z + t[k].w*t[k].w;
        float dx = a[k].x-t[k].x, dy = a[k].y-t[k].y, dz = a[k].z-t[k].z, dw = a[k].w-t[k].w;
        sd += dx*dx + dy*dy + dz*dz + dw*dw;
    }
#pragma unroll
    for (int o = 16; o; o >>= 1) {
        si += __shfl_xor(si, o); st += __shfl_xor(st, o); sd += __shfl_xor(sd, o);
    }
    float ii = 1.f / fmaxf(sqrtf(si), 1e-12f);
    float it = 1.f / fmaxf(sqrtf(st), 1e-12f);
    if (c == 0) { inv_in[row] = ii; inv_tg[row] = it; ploss[row] = sd * (1.f / DIM); }
    if constexpr (PRE != 0) {
#pragma unroll
        for (int k = 0; k < 3; ++k) {
            us8 ua, ut;
            ua[0]=f2bf(a[2*k].x*ii);  ua[1]=f2bf(a[2*k].y*ii);
            ua[2]=f2bf(a[2*k].z*ii);  ua[3]=f2bf(a[2*k].w*ii);
            ua[4]=f2bf(a[2*k+1].x*ii);ua[5]=f2bf(a[2*k+1].y*ii);
            ua[6]=f2bf(a[2*k+1].z*ii);ua[7]=f2bf(a[2*k+1].w*ii);
            ut[0]=f2bf(t[2*k].x*it);  ut[1]=f2bf(t[2*k].y*it);
            ut[2]=f2bf(t[2*k].z*it);  ut[3]=f2bf(t[2*k].w*it);
            ut[4]=f2bf(t[2*k+1].x*it);ut[5]=f2bf(t[2*k+1].y*it);
            ut[6]=f2bf(t[2*k+1].z*it);ut[7]=f2bf(t[2*k+1].w*it);
            *(us8*)(in_n + (size_t)row * DIM + 8*c + 256*k) = ua;
            *(us8*)(tg_n + (size_t)row * DIM + 8*c + 256*k) = ut;
        }
    }
}

// ------------------------------------------- weights pipeline (all f32!)
// tf/idf denominators are near-zero means — bf16 upstream of the
// reciprocals flips signs (round-3 failure). Everything here stays f32.

__global__ __launch_bounds__(64) void k_bsum1(const float* __restrict__ tg,
                                              const float* __restrict__ inv_tg,
                                              float* __restrict__ psum) {
    int b = blockIdx.x, y = blockIdx.y, h = blockIdx.z;
    int d0 = y * 256 + threadIdx.x * 4;
    const float* base = tg + (size_t)(b * PP + h * 64) * DIM + d0;
    const float* itg  = inv_tg + b * PP + h * 64;
    float4 s = { 0.f, 0.f, 0.f, 0.f };
    for (int r = 0; r < 64; ++r) {
        float4 v = *(const float4*)(base + (size_t)r * DIM);
        float w = itg[r];
        s.x += v.x * w; s.y += v.y * w; s.z += v.z * w; s.w += v.w * w;
    }
    *(float4*)(psum + (size_t)(b * 4 + h) * DIM + d0) = s;
}

__global__ __launch_bounds__(256) void k_bsum2(const float* __restrict__ psum,
                                               float* __restrict__ bsum,
                                               float* __restrict__ va) {
    int d = blockIdx.x * 256 + threadIdx.x;
    if (d >= DIM) return;
    float g = 0.f;
    for (int b = 0; b < BT; ++b) {
        float s = psum[(size_t)(b * 4 + 0) * DIM + d] + psum[(size_t)(b * 4 + 1) * DIM + d]
                + psum[(size_t)(b * 4 + 2) * DIM + d] + psum[(size_t)(b * 4 + 3) * DIM + d];
        bsum[b * DIM + d] = s;
        g += s;
    }
    va[d] = g * (1.f / NROWS);
}

__global__ __launch_bounds__(256) void k_wdots(const float* __restrict__ tg,
                                               const float* __restrict__ inv_tg,
                                               const float* __restrict__ bsum,
                                               const float* __restrict__ va,
                                               float* __restrict__ wraw) {
    int wave = threadIdx.x >> 6, lane = threadIdx.x & 63;
    int gw = blockIdx.x * 4 + wave;
#pragma unroll
    for (int rr = 0; rr < 4; ++rr) {
        int row = gw * 4 + rr;
        int b   = row >> 8;
        const float4* t4 = (const float4*)(tg + (size_t)row * DIM);
        const float4* b4 = (const float4*)(bsum + b * DIM);
        const float4* a4 = (const float4*)va;
        float db = 0.f, da = 0.f;
#pragma unroll
        for (int v = 0; v < 3; ++v) {
            float4 t = t4[lane + 64 * v];
            float4 x = b4[lane + 64 * v];
            float4 y = a4[lane + 64 * v];
            db += t.x * x.x + t.y * x.y + t.z * x.z + t.w * x.w;
            da += t.x * y.x + t.y * y.y + t.z * y.z + t.w * y.w;
        }
#pragma unroll
        for (int o = 32; o; o >>= 1) { db += __shfl_xor(db, o); da += __shfl_xor(da, o); }
        if (lane == 0) {
            float itg = inv_tg[row];
            db *= itg; da *= itg;
            wraw[row] = (1.f / (db * (1.f / PP) + EPSF)) * (1.f / (da + EPSF));
        }
    }
}

__global__ __launch_bounds__(256) void k_wfinal(const float* __restrict__ wraw,
                                                const float* __restrict__ ploss,
                                                float* __restrict__ weights,
                                                float* __restrict__ simpart) {
    __shared__ float red[256];
    int b = blockIdx.x, p = threadIdx.x, row = b * PP + p;
    float w = wraw[row];
    red[p] = w; __syncthreads();
    for (int s = 128; s; s >>= 1) { if (p < s) red[p] += red[p + s]; __syncthreads(); }
    float wn = w / (red[0] + EPSF);
    weights[row] = wn;
    __syncthreads();
    red[p] = wn * ploss[row]; __syncthreads();
    for (int s = 128; s; s >>= 1) { if (p < s) red[p] += red[p + s]; __syncthreads(); }
    if (p == 0) simpart[b] = red[0];
}

// ---------------------------------------------------------------- kernel 4
// Dual-gram v3: 640 WGs = 64 blocks x 10 symmetric 64x64 tile pairs.
// 4 waves; each wave computes a 32x32 quadrant of BOTH grams.
// bf16 staging from PRE-materialized in_n/tg_n; double-buffered LDS,
// ONE barrier per K-step; XOR chunk swizzle cc^(row&3).
__global__ __launch_bounds__(256, 3) void k_gram(const unsigned short* __restrict__ in_n,
                                                 const unsigned short* __restrict__ tg_n,
                                                 const float* __restrict__ weights,
                                                 float* __restrict__ grampart) {
    __shared__ __align__(16) unsigned short L[2][4][64 * GKC];
    __shared__ float red[256];

    const int wg  = blockIdx.x;
    const int xcd = wg & 7, j = wg >> 3;          // 640 = 8 XCD chunks x 80
    const int b   = xcd * 8 + j / NTILE;
    const int t   = j % NTILE;
    int ti, tj;
    if (t < 4)      { ti = 0; tj = t; }
    else if (t < 7) { ti = 1; tj = t - 3; }
    else if (t < 9) { ti = 2; tj = t - 5; }
    else            { ti = 3; tj = 3; }
    const int pr = ti * 64, qc = tj * 64;
    const bool diag = (ti == tj);
    const float factor = diag ? 1.f : 2.f;
    const int bP = b * PP;

    const int tid = threadIdx.x, lane = tid & 63, wave = tid >> 6;

    // staging role: wave w owns LDS matrix w: 0=A_in, 1=A_tg, 2=B_in, 3=B_tg
    const unsigned short* smat = (wave & 1) ? tg_n : in_n;
    const int  srow0   = bP + ((wave < 2) ? pr : qc);
    const bool doStage = !(diag && wave >= 2);
    const int  srl = lane >> 2;              // row within 16-row group
    const int  scc = lane & 3;               // source 16B chunk (8 bf16)
    const int  wcc = scc ^ (srl & 3);        // swizzled LDS chunk

    us8 sreg[4];
    auto LD = [&](int k0) {
        if (!doStage) return;
#pragma unroll
        for (int i = 0; i < 4; ++i)
            sreg[i] = *(const us8*)(smat + (size_t)(srow0 + 16 * i + srl) * DIM + k0 + scc * 8);
    };
    auto WR = [&](int cur) {
        if (!doStage) return;
#pragma unroll
        for (int i = 0; i < 4; ++i)
            *(us8*)&L[cur][wave][(16 * i + srl) * GKC + wcc * 8] = sreg[i];
    };

    const int ar0 = (wave >> 1) * 32, bc0 = (wave & 1) * 32;
    const int rl = lane & 15, kc = lane >> 4;
    const int bi_ = diag ? 0 : 2, bt_ = diag ? 1 : 3;

    f32x4 accI[2][2], accT[2][2];
#pragma unroll
    for (int m = 0; m < 2; ++m)
#pragma unroll
        for (int n = 0; n < 2; ++n) {
            f32x4 z = { 0.f, 0.f, 0.f, 0.f };
            accI[m][n] = z; accT[m][n] = z;
        }

    LD(0); WR(0);
    int cur = 0;
    const int NS = DIM / GKC;   // 24
    for (int ks = 0; ks < NS; ++ks) {
        if (ks + 1 < NS) LD((ks + 1) * GKC);   // issue next loads early
        __syncthreads();                        // L[cur] ready for all
        bf16x8 aI[2], aT[2], bI[2], bT[2];
#pragma unroll
        for (int m = 0; m < 2; ++m) {
            int row = ar0 + m * 16 + rl;
            int off = row * GKC + ((kc ^ (row & 3)) << 3);
            aI[m] = *(const bf16x8*)&L[cur][0][off];
            aT[m] = *(const bf16x8*)&L[cur][1][off];
        }
#pragma unroll
        for (int n = 0; n < 2; ++n) {
            int row = bc0 + n * 16 + rl;
            int off = row * GKC + ((kc ^ (row & 3)) << 3);
            bI[n] = *(const bf16x8*)&L[cur][bi_][off];
            bT[n] = *(const bf16x8*)&L[cur][bt_][off];
        }
#pragma unroll
        for (int m = 0; m < 2; ++m)
#pragma unroll
            for (int n = 0; n < 2; ++n) {
                accI[m][n] = __builtin_amdgcn_mfma_f32_16x16x32_bf16(aI[m], bI[n], accI[m][n], 0, 0, 0);
                accT[m][n] = __builtin_amdgcn_mfma_f32_16x16x32_bf16(aT[m], bT[n], accT[m][n], 0, 0, 0);
            }
        if (ks + 1 < NS) WR(cur ^ 1);          // fill alternate buffer
        cur ^= 1;
    }

    // epilogue: weighted squared diff.  C/D: col=lane&15, row=(lane>>4)*4+r
    const int r4 = lane >> 4, cl = lane & 15;
    float wq[2], wp[2][4];
#pragma unroll
    for (int n = 0; n < 2; ++n) wq[n] = weights[bP + qc + bc0 + n * 16 + cl];
#pragma unroll
    for (int m = 0; m < 2; ++m)
#pragma unroll
        for (int r = 0; r < 4; ++r) wp[m][r] = weights[bP + pr + ar0 + m * 16 + r4 * 4 + r];
    float local = 0.f;
#pragma unroll
    for (int m = 0; m < 2; ++m)
#pragma unroll
        for (int n = 0; n < 2; ++n)
#pragma unroll
            for (int r = 0; r < 4; ++r) {
                float d = accI[m][n][r] - accT[m][n][r];
                local += wp[m][r] * wq[n] * d * d;
            }
    local *= factor;
    red[tid] = local; __syncthreads();
    for (int s = 128; s; s >>= 1) { if (tid < s) red[tid] += red[tid + s]; __syncthreads(); }
    if (tid == 0) grampart[wg] = red[0];
}

// ------------------------------------------- fallback gram (f32 staging),
// used only if workspace can't hold the bf16 copies. Round-5 proven.
#define LP 40
__global__ __launch_bounds__(256) void k_gram_f32(const float* __restrict__ in,
                                                  const float* __restrict__ tg,
                                                  const float* __restrict__ inv_in,
                                                  const float* __restrict__ inv_tg,
                                                  const float* __restrict__ weights,
                                                  float* __restrict__ grampart) {
    __shared__ __align__(16) unsigned short LA0[128 * LP];
    __shared__ __align__(16) unsigned short LA1[128 * LP];
    __shared__ __align__(16) unsigned short LB0[128 * LP];
    __shared__ __align__(16) unsigned short LB1[128 * LP];
    __shared__ float red[256];

    const int wg  = blockIdx.x;
    const int xcd = wg & 7, j = wg >> 3;
    const int b   = xcd * 8 + j / 3;
    const int t3  = j % 3;
    const int pr  = (t3 == 2) ? 128 : 0;
    const int qc  = (t3 == 0) ? 0 : 128;
    const bool diag = (pr == qc);
    const float factor = diag ? 1.f : 2.f;

    const int tid  = threadIdx.x;
    const int lane = tid & 63;
    const int wave = tid >> 6;
    const int wr = (wave >> 1) * 64, wc = (wave & 1) * 64;
    const int bP = b * PP;

    const int strow = tid >> 2;
    const int skq   = tid & 3;
    const int sw    = (strow >> 3) & 3;

    const float* srcf[4] = { in, tg, in, tg };
    unsigned short* ldst[4] = { LA0, LA1, LB0, LB1 };

    size_t g[4][2];
#pragma unroll
    for (int h = 0; h < 2; ++h) {
        g[0][h] = (size_t)(bP + pr + strow + h * 64) * DIM + skq * 8;
        g[1][h] = g[0][h];
        g[2][h] = (size_t)(bP + qc + strow + h * 64) * DIM + skq * 8;
        g[3][h] = g[2][h];
    }
    float scl[4][2];
#pragma unroll
    for (int h = 0; h < 2; ++h) {
        scl[0][h] = inv_in[bP + pr + strow + h * 64];
        scl[1][h] = inv_tg[bP + pr + strow + h * 64];
        scl[2][h] = inv_in[bP + qc + strow + h * 64];
        scl[3][h] = inv_tg[bP + qc + strow + h * 64];
    }

    float4 pfa[4][2], pfb[4][2];

    auto STAGE_LOAD = [&](int k0) {
#pragma unroll
        for (int bi = 0; bi < 4; ++bi) {
            if (bi >= 2 && diag) continue;
#pragma unroll
            for (int h = 0; h < 2; ++h) {
                pfa[bi][h] = *(const float4*)(srcf[bi] + g[bi][h] + k0);
                pfb[bi][h] = *(const float4*)(srcf[bi] + g[bi][h] + k0 + 4);
            }
        }
    };
    auto STAGE_WRITE = [&]() {
#pragma unroll
        for (int bi = 0; bi < 4; ++bi) {
            if (bi >= 2 && diag) continue;
#pragma unroll
            for (int h = 0; h < 2; ++h) {
                us8 v;
                float s = scl[bi][h];
                float4 x = pfa[bi][h], y = pfb[bi][h];
                v[0] = f2bf(x.x * s); v[1] = f2bf(x.y * s);
                v[2] = f2bf(x.z * s); v[3] = f2bf(x.w * s);
                v[4] = f2bf(y.x * s); v[5] = f2bf(y.y * s);
                v[6] = f2bf(y.z * s); v[7] = f2bf(y.w * s);
                int row = strow + h * 64;
                *(us8*)&ldst[bi][row * LP + (skq ^ sw) * 8] = v;
            }
        }
    };

    const unsigned short* RB0 = diag ? LA0 : LB0;
    const unsigned short* RB1 = diag ? LA1 : LB1;

    f32x4 accI[4][4], accT[4][4];
#pragma unroll
    for (int m = 0; m < 4; ++m)
#pragma unroll
        for (int n = 0; n < 4; ++n) {
            f32x4 z = { 0.f, 0.f, 0.f, 0.f };
            accI[m][n] = z; accT[m][n] = z;
        }

    STAGE_LOAD(0);
    for (int ks = 0; ks < DIM / GKC; ++ks) {
        __syncthreads();
        STAGE_WRITE();
        __syncthreads();
        if (ks + 1 < DIM / GKC) STAGE_LOAD(GKC * (ks + 1));

        bf16x8 aI[4], aT[4], bI[4], bT[4];
#pragma unroll
        for (int m = 0; m < 4; ++m) {
            int row = wr + m * 16 + (lane & 15);
            int off = row * LP + (((lane >> 4) ^ ((row >> 3) & 3))) * 8;
            aI[m] = *(const bf16x8*)&LA0[off];
            aT[m] = *(const bf16x8*)&LA1[off];
        }
#pragma unroll
        for (int n = 0; n < 4; ++n) {
            int row = wc + n * 16 + (lane & 15);
            int off = row * LP + (((lane >> 4) ^ ((row >> 3) & 3))) * 8;
            bI[n] = *(const bf16x8*)&RB0[off];
            bT[n] = *(const bf16x8*)&RB1[off];
        }
#pragma unroll
        for (int m = 0; m < 4; ++m)
#pragma unroll
            for (int n = 0; n < 4; ++n) {
                accI[m][n] = __builtin_amdgcn_mfma_f32_16x16x32_bf16(aI[m], bI[n], accI[m][n], 0, 0, 0);
                accT[m][n] = __builtin_amdgcn_mfma_f32_16x16x32_bf16(aT[m], bT[n], accT[m][n], 0, 0, 0);
            }
    }

    const int r4 = lane >> 4, cl = lane & 15;
    float wq[4], wp[4][4];
#pragma unroll
    for (int n = 0; n < 4; ++n) wq[n] = weights[bP + qc + wc + n * 16 + cl];
#pragma unroll
    for (int m = 0; m < 4; ++m)
#pragma unroll
        for (int r = 0; r < 4; ++r) wp[m][r] = weights[bP + pr + wr + m * 16 + r4 * 4 + r];
    float local = 0.f;
#pragma unroll
    for (int m = 0; m < 4; ++m)
#pragma unroll
        for (int n = 0; n < 4; ++n)
#pragma unroll
            for (int r = 0; r < 4; ++r) {
                float d = accI[m][n][r] - accT[m][n][r];
                local += wp[m][r] * wq[n] * d * d;
            }
    local *= factor;
    red[tid] = local; __syncthreads();
    for (int s = 128; s; s >>= 1) { if (tid < s) red[tid] += red[tid + s]; __syncthreads(); }
    if (tid == 0) grampart[wg] = red[0];
}

// ---------------------------------------------------------------- kernel 5
__global__ __launch_bounds__(256) void k_final(const float* __restrict__ simpart,
                                               const float* __restrict__ grampart,
                                               int ngram,
                                               float* __restrict__ out) {
    __shared__ float red[256];
    int t = threadIdx.x;
    float v = (t < BT) ? simpart[t] : 0.f;
    float g = 0.f;
    for (int i = t; i < ngram; i += 256) g += grampart[i];
    v += 10.f * g;
    red[t] = v; __syncthreads();
    for (int s = 128; s; s >>= 1) { if (t < s) red[t] += red[t + s]; __syncthreads(); }
    if (t == 0) out[0] = red[0] * (1.f / BT);
}

// ---------------------------------------------------------------- launch
extern "C" void kernel_launch(void* const* d_in, const int* in_sizes, int n_in,
                              void* d_out, int out_size, void* d_ws, size_t ws_size,
                              hipStream_t stream) {
    (void)in_sizes; (void)n_in; (void)out_size;
    const float* in = (const float*)d_in[0];
    const float* tg = (const float*)d_in[1];

    const size_t bfBytes   = (size_t)NROWS * DIM * 2;     // one bf16 matrix
    const size_t floatsOff = 2 * bfBytes;
    const size_t fCount    = 5 * (size_t)NROWS + 5 * (size_t)BT * DIM + DIM + BT + NGRAM;
    const size_t needed    = floatsOff + fCount * 4;
    const bool   pre       = ws_size >= needed;

    char* wsb = (char*)d_ws;
    unsigned short* in_n = nullptr;
    unsigned short* tg_n = nullptr;
    float* fbase;
    if (pre) {
        in_n  = (unsigned short*)wsb;
        tg_n  = (unsigned short*)(wsb + bfBytes);
        fbase = (float*)(wsb + floatsOff);
    } else {
        fbase = (float*)wsb;
    }
    float* inv_in  = fbase;
    float* inv_tg  = fbase + NROWS;
    float* ploss   = fbase + 2 * (size_t)NROWS;
    float* wraw    = fbase + 3 * (size_t)NROWS;
    float* weights = fbase + 4 * (size_t)NROWS;
    float* psum    = fbase + 5 * (size_t)NROWS;            // 4*BT*DIM
    float* bsum    = psum + 4 * (size_t)BT * DIM;          // BT*DIM
    float* va      = bsum + (size_t)BT * DIM;              // DIM
    float* simpart = va + DIM;                             // BT
    float* grampart= simpart + BT;                         // NGRAM

    if (pre) {
        k_norms<1><<<NROWS / 16, 512, 0, stream>>>(in, tg, inv_in, inv_tg, ploss, in_n, tg_n);
    } else {
        k_norms<0><<<NROWS / 16, 512, 0, stream>>>(in, tg, inv_in, inv_tg, ploss, nullptr, nullptr);
    }
    k_bsum1<<<dim3(BT, 3, 4), 64, 0, stream>>>(tg, inv_tg, psum);
    k_bsum2<<<3, 256, 0, stream>>>(psum, bsum, va);
    k_wdots<<<NROWS / 16, 256, 0, stream>>>(tg, inv_tg, bsum, va, wraw);
    k_wfinal<<<BT, 256, 0, stream>>>(wraw, ploss, weights, simpart);
    if (pre) {
        k_gram<<<NGRAM, 256, 0, stream>>>(in_n, tg_n, weights, grampart);
        k_final<<<1, 256, 0, stream>>>(simpart, grampart, NGRAM, (float*)d_out);
    } else {
        k_gram_f32<<<192, 256, 0, stream>>>(in, tg, inv_in, inv_tg, weights, grampart);
        k_final<<<1, 256, 0, stream>>>(simpart, grampart, 192, (float*)d_out);
    }
}

// Round 7
// 69.605 us; speedup vs baseline: 1.2885x; 1.1369x over previous
//
#include <hip/hip_runtime.h>
#include <hip/hip_bf16.h>

#define NROWS 16384
#define DIM   768
#define PP    256
#define BT    64
#define EPSF  1e-6f
#define GKC   32     // k_gram K-chunk
#define NTILE 10     // symmetric 64x64 tile pairs per block
#define NGRAM (BT * NTILE)   // 640 WGs
#define SPITCH 776   // LDS f32 pitch for psum staging (768+8, 16B-aligned)
#define NWG_N  (NROWS / 8)   // 2048 k_norms WGs (8 rows each)

typedef short          bf16x8 __attribute__((ext_vector_type(8)));
typedef float          f32x4  __attribute__((ext_vector_type(4)));
typedef unsigned short us8    __attribute__((ext_vector_type(8)));

__device__ __forceinline__ unsigned short f2bf(float x) {
    __hip_bfloat16 h = __float2bfloat16(x);
    return *reinterpret_cast<unsigned short*>(&h);
}

// ---------------------------------------------------------------- kernel 1
// Per-row inv-norms + patch_loss + bf16 normalized copies (PRE) + fused
// per-WG partial block-sum of normalized target rows (replaces k_bsum1).
// 256 threads = 4 waves; each half-wave (32 lanes) owns one row; 8 rows/WG,
// all rows within one bt-block (32 WGs per block).
template<int PRE>
__global__ __launch_bounds__(256) void k_norms(const float* __restrict__ in,
                                               const float* __restrict__ tg,
                                               float* __restrict__ inv_in,
                                               float* __restrict__ inv_tg,
                                               float* __restrict__ ploss,
                                               unsigned short* __restrict__ in_n,
                                               unsigned short* __restrict__ tg_n,
                                               float* __restrict__ psum) {
    __shared__ __align__(16) float S[8][SPITCH];
    const int r   = threadIdx.x >> 5;          // row within WG (0..7)
    const int c   = threadIdx.x & 31;
    const int row = blockIdx.x * 8 + r;
    const float4* ip = (const float4*)(in + (size_t)row * DIM);
    const float4* tp = (const float4*)(tg + (size_t)row * DIM);
    float4 a[6], t[6];
#pragma unroll
    for (int k = 0; k < 3; ++k) {
        a[2*k]   = ip[2*c + 64*k];  a[2*k+1] = ip[2*c + 64*k + 1];
        t[2*k]   = tp[2*c + 64*k];  t[2*k+1] = tp[2*c + 64*k + 1];
    }
    float si = 0.f, st = 0.f, sd = 0.f;
#pragma unroll
    for (int k = 0; k < 6; ++k) {
        si += a[k].x*a[k].x + a[k].y*a[k].y + a[k].z*a[k].z + a[k].w*a[k].w;
        st += t[k].x*t[k].x + t[k].y*t[k].y + t[k].z*t[k].z + t[k].w*t[k].w;
        float dx = a[k].x-t[k].x, dy = a[k].y-t[k].y, dz = a[k].z-t[k].z, dw = a[k].w-t[k].w;
        sd += dx*dx + dy*dy + dz*dz + dw*dw;
    }
#pragma unroll
    for (int o = 16; o; o >>= 1) {      // reduce within 32-lane half-wave
        si += __shfl_xor(si, o); st += __shfl_xor(st, o); sd += __shfl_xor(sd, o);
    }
    float ii = 1.f / fmaxf(sqrtf(si), 1e-12f);
    float it = 1.f / fmaxf(sqrtf(st), 1e-12f);
    if (c == 0) { inv_in[row] = ii; inv_tg[row] = it; ploss[row] = sd * (1.f / DIM); }

    // stage normalized tg (f32) for the fused block-sum
#pragma unroll
    for (int k = 0; k < 3; ++k) {
        float4 u0 = t[2*k], u1 = t[2*k+1];
        u0.x*=it; u0.y*=it; u0.z*=it; u0.w*=it;
        u1.x*=it; u1.y*=it; u1.z*=it; u1.w*=it;
        *(float4*)&S[r][8*c + 256*k]     = u0;
        *(float4*)&S[r][8*c + 256*k + 4] = u1;
    }

    if constexpr (PRE != 0) {
#pragma unroll
        for (int k = 0; k < 3; ++k) {
            us8 ua, ut;
            ua[0]=f2bf(a[2*k].x*ii);  ua[1]=f2bf(a[2*k].y*ii);
            ua[2]=f2bf(a[2*k].z*ii);  ua[3]=f2bf(a[2*k].w*ii);
            ua[4]=f2bf(a[2*k+1].x*ii);ua[5]=f2bf(a[2*k+1].y*ii);
            ua[6]=f2bf(a[2*k+1].z*ii);ua[7]=f2bf(a[2*k+1].w*ii);
            ut[0]=f2bf(t[2*k].x*it);  ut[1]=f2bf(t[2*k].y*it);
            ut[2]=f2bf(t[2*k].z*it);  ut[3]=f2bf(t[2*k].w*it);
            ut[4]=f2bf(t[2*k+1].x*it);ut[5]=f2bf(t[2*k+1].y*it);
            ut[6]=f2bf(t[2*k+1].z*it);ut[7]=f2bf(t[2*k+1].w*it);
            *(us8*)(in_n + (size_t)row * DIM + 8*c + 256*k) = ua;
            *(us8*)(tg_n + (size_t)row * DIM + 8*c + 256*k) = ut;
        }
    }

    __syncthreads();
    // deterministic 8-row reduce: thread t handles d = t, t+256, t+512
#pragma unroll
    for (int q = 0; q < 3; ++q) {
        int d = threadIdx.x + 256 * q;
        float s = 0.f;
#pragma unroll
        for (int rr = 0; rr < 8; ++rr) s += S[rr][d];
        psum[(size_t)blockIdx.x * DIM + d] = s;
    }
}

// ------------------------------------------- weights pipeline (all f32!)
// tf/idf denominators are near-zero means — bf16 upstream of the
// reciprocals flips signs (round-3 failure). Everything here stays f32.

// merge 32 psum partials per block -> bsum[b][d]
__global__ __launch_bounds__(256) void k_bsum2(const float* __restrict__ psum,
                                               float* __restrict__ bsum) {
    int b = blockIdx.x, d = blockIdx.y * 256 + threadIdx.x;
    float s = 0.f;
#pragma unroll 8
    for (int i = 0; i < 32; ++i)
        s += psum[(size_t)(b * 32 + i) * DIM + d];
    bsum[b * DIM + d] = s;
}

// global mean vector
__global__ __launch_bounds__(256) void k_gmean(const float* __restrict__ bsum,
                                               float* __restrict__ va) {
    int d = blockIdx.x * 256 + threadIdx.x;
    float g = 0.f;
    for (int b = 0; b < BT; ++b) g += bsum[b * DIM + d];
    va[d] = g * (1.f / NROWS);
}

__global__ __launch_bounds__(256) void k_wdots(const float* __restrict__ tg,
                                               const float* __restrict__ inv_tg,
                                               const float* __restrict__ bsum,
                                               const float* __restrict__ va,
                                               float* __restrict__ wraw) {
    int wave = threadIdx.x >> 6, lane = threadIdx.x & 63;
    int gw = blockIdx.x * 4 + wave;
#pragma unroll
    for (int rr = 0; rr < 4; ++rr) {
        int row = gw * 4 + rr;
        int b   = row >> 8;
        const float4* t4 = (const float4*)(tg + (size_t)row * DIM);
        const float4* b4 = (const float4*)(bsum + b * DIM);
        const float4* a4 = (const float4*)va;
        float db = 0.f, da = 0.f;
#pragma unroll
        for (int v = 0; v < 3; ++v) {
            float4 t = t4[lane + 64 * v];
            float4 x = b4[lane + 64 * v];
            float4 y = a4[lane + 64 * v];
            db += t.x * x.x + t.y * x.y + t.z * x.z + t.w * x.w;
            da += t.x * y.x + t.y * y.y + t.z * y.z + t.w * y.w;
        }
#pragma unroll
        for (int o = 32; o; o >>= 1) { db += __shfl_xor(db, o); da += __shfl_xor(da, o); }
        if (lane == 0) {
            float itg = inv_tg[row];
            db *= itg; da *= itg;
            wraw[row] = (1.f / (db * (1.f / PP) + EPSF)) * (1.f / (da + EPSF));
        }
    }
}

__global__ __launch_bounds__(256) void k_wfinal(const float* __restrict__ wraw,
                                                const float* __restrict__ ploss,
                                                float* __restrict__ weights,
                                                float* __restrict__ simpart) {
    __shared__ float red[256];
    int b = blockIdx.x, p = threadIdx.x, row = b * PP + p;
    float w = wraw[row];
    red[p] = w; __syncthreads();
    for (int s = 128; s; s >>= 1) { if (p < s) red[p] += red[p + s]; __syncthreads(); }
    float wn = w / (red[0] + EPSF);
    weights[row] = wn;
    __syncthreads();
    red[p] = wn * ploss[row]; __syncthreads();
    for (int s = 128; s; s >>= 1) { if (p < s) red[p] += red[p + s]; __syncthreads(); }
    if (p == 0) simpart[b] = red[0];
}

// ---------------------------------------------------------------- kernel 4
// Dual-gram: 640 WGs = 64 blocks x 10 symmetric 64x64 tile pairs.
// 4 waves; each wave computes a 32x32 quadrant of BOTH grams.
__global__ __launch_bounds__(256, 3) void k_gram(const unsigned short* __restrict__ in_n,
                                                 const unsigned short* __restrict__ tg_n,
                                                 const float* __restrict__ weights,
                                                 float* __restrict__ grampart) {
    __shared__ __align__(16) unsigned short L[2][4][64 * GKC];
    __shared__ float red[256];

    const int wg  = blockIdx.x;
    const int xcd = wg & 7, j = wg >> 3;          // 640 = 8 XCD chunks x 80
    const int b   = xcd * 8 + j / NTILE;
    const int t   = j % NTILE;
    int ti, tj;
    if (t < 4)      { ti = 0; tj = t; }
    else if (t < 7) { ti = 1; tj = t - 3; }
    else if (t < 9) { ti = 2; tj = t - 5; }
    else            { ti = 3; tj = 3; }
    const int pr = ti * 64, qc = tj * 64;
    const bool diag = (ti == tj);
    const float factor = diag ? 1.f : 2.f;
    const int bP = b * PP;

    const int tid = threadIdx.x, lane = tid & 63, wave = tid >> 6;

    const unsigned short* smat = (wave & 1) ? tg_n : in_n;
    const int  srow0   = bP + ((wave < 2) ? pr : qc);
    const bool doStage = !(diag && wave >= 2);
    const int  srl = lane >> 2;
    const int  scc = lane & 3;
    const int  wcc = scc ^ (srl & 3);

    us8 sreg[4];
    auto LD = [&](int k0) {
        if (!doStage) return;
#pragma unroll
        for (int i = 0; i < 4; ++i)
            sreg[i] = *(const us8*)(smat + (size_t)(srow0 + 16 * i + srl) * DIM + k0 + scc * 8);
    };
    auto WR = [&](int cur) {
        if (!doStage) return;
#pragma unroll
        for (int i = 0; i < 4; ++i)
            *(us8*)&L[cur][wave][(16 * i + srl) * GKC + wcc * 8] = sreg[i];
    };

    const int ar0 = (wave >> 1) * 32, bc0 = (wave & 1) * 32;
    const int rl = lane & 15, kc = lane >> 4;
    const int bi_ = diag ? 0 : 2, bt_ = diag ? 1 : 3;

    f32x4 accI[2][2], accT[2][2];
#pragma unroll
    for (int m = 0; m < 2; ++m)
#pragma unroll
        for (int n = 0; n < 2; ++n) {
            f32x4 z = { 0.f, 0.f, 0.f, 0.f };
            accI[m][n] = z; accT[m][n] = z;
        }

    LD(0); WR(0);
    int cur = 0;
    const int NS = DIM / GKC;   // 24
    for (int ks = 0; ks < NS; ++ks) {
        if (ks + 1 < NS) LD((ks + 1) * GKC);
        __syncthreads();
        bf16x8 aI[2], aT[2], bI[2], bT[2];
#pragma unroll
        for (int m = 0; m < 2; ++m) {
            int row = ar0 + m * 16 + rl;
            int off = row * GKC + ((kc ^ (row & 3)) << 3);
            aI[m] = *(const bf16x8*)&L[cur][0][off];
            aT[m] = *(const bf16x8*)&L[cur][1][off];
        }
#pragma unroll
        for (int n = 0; n < 2; ++n) {
            int row = bc0 + n * 16 + rl;
            int off = row * GKC + ((kc ^ (row & 3)) << 3);
            bI[n] = *(const bf16x8*)&L[cur][bi_][off];
            bT[n] = *(const bf16x8*)&L[cur][bt_][off];
        }
#pragma unroll
        for (int m = 0; m < 2; ++m)
#pragma unroll
            for (int n = 0; n < 2; ++n) {
                accI[m][n] = __builtin_amdgcn_mfma_f32_16x16x32_bf16(aI[m], bI[n], accI[m][n], 0, 0, 0);
                accT[m][n] = __builtin_amdgcn_mfma_f32_16x16x32_bf16(aT[m], bT[n], accT[m][n], 0, 0, 0);
            }
        if (ks + 1 < NS) WR(cur ^ 1);
        cur ^= 1;
    }

    const int r4 = lane >> 4, cl = lane & 15;
    float wq[2], wp[2][4];
#pragma unroll
    for (int n = 0; n < 2; ++n) wq[n] = weights[bP + qc + bc0 + n * 16 + cl];
#pragma unroll
    for (int m = 0; m < 2; ++m)
#pragma unroll
        for (int r = 0; r < 4; ++r) wp[m][r] = weights[bP + pr + ar0 + m * 16 + r4 * 4 + r];
    float local = 0.f;
#pragma unroll
    for (int m = 0; m < 2; ++m)
#pragma unroll
        for (int n = 0; n < 2; ++n)
#pragma unroll
            for (int r = 0; r < 4; ++r) {
                float d = accI[m][n][r] - accT[m][n][r];
                local += wp[m][r] * wq[n] * d * d;
            }
    local *= factor;
    red[tid] = local; __syncthreads();
    for (int s = 128; s; s >>= 1) { if (tid < s) red[tid] += red[tid + s]; __syncthreads(); }
    if (tid == 0) grampart[wg] = red[0];
}

// ------------------------------------------- fallback gram (f32 staging),
// used only if workspace can't hold the bf16 copies.
#define LP 40
__global__ __launch_bounds__(256) void k_gram_f32(const float* __restrict__ in,
                                                  const float* __restrict__ tg,
                                                  const float* __restrict__ inv_in,
                                                  const float* __restrict__ inv_tg,
                                                  const float* __restrict__ weights,
                                                  float* __restrict__ grampart) {
    __shared__ __align__(16) unsigned short LA0[128 * LP];
    __shared__ __align__(16) unsigned short LA1[128 * LP];
    __shared__ __align__(16) unsigned short LB0[128 * LP];
    __shared__ __align__(16) unsigned short LB1[128 * LP];
    __shared__ float red[256];

    const int wg  = blockIdx.x;
    const int xcd = wg & 7, j = wg >> 3;
    const int b   = xcd * 8 + j / 3;
    const int t3  = j % 3;
    const int pr  = (t3 == 2) ? 128 : 0;
    const int qc  = (t3 == 0) ? 0 : 128;
    const bool diag = (pr == qc);
    const float factor = diag ? 1.f : 2.f;

    const int tid  = threadIdx.x;
    const int lane = tid & 63;
    const int wave = tid >> 6;
    const int wr = (wave >> 1) * 64, wc = (wave & 1) * 64;
    const int bP = b * PP;

    const int strow = tid >> 2;
    const int skq   = tid & 3;
    const int sw    = (strow >> 3) & 3;

    const float* srcf[4] = { in, tg, in, tg };
    unsigned short* ldst[4] = { LA0, LA1, LB0, LB1 };

    size_t g[4][2];
#pragma unroll
    for (int h = 0; h < 2; ++h) {
        g[0][h] = (size_t)(bP + pr + strow + h * 64) * DIM + skq * 8;
        g[1][h] = g[0][h];
        g[2][h] = (size_t)(bP + qc + strow + h * 64) * DIM + skq * 8;
        g[3][h] = g[2][h];
    }
    float scl[4][2];
#pragma unroll
    for (int h = 0; h < 2; ++h) {
        scl[0][h] = inv_in[bP + pr + strow + h * 64];
        scl[1][h] = inv_tg[bP + pr + strow + h * 64];
        scl[2][h] = inv_in[bP + qc + strow + h * 64];
        scl[3][h] = inv_tg[bP + qc + strow + h * 64];
    }

    float4 pfa[4][2], pfb[4][2];

    auto STAGE_LOAD = [&](int k0) {
#pragma unroll
        for (int bi = 0; bi < 4; ++bi) {
            if (bi >= 2 && diag) continue;
#pragma unroll
            for (int h = 0; h < 2; ++h) {
                pfa[bi][h] = *(const float4*)(srcf[bi] + g[bi][h] + k0);
                pfb[bi][h] = *(const float4*)(srcf[bi] + g[bi][h] + k0 + 4);
            }
        }
    };
    auto STAGE_WRITE = [&]() {
#pragma unroll
        for (int bi = 0; bi < 4; ++bi) {
            if (bi >= 2 && diag) continue;
#pragma unroll
            for (int h = 0; h < 2; ++h) {
                us8 v;
                float s = scl[bi][h];
                float4 x = pfa[bi][h], y = pfb[bi][h];
                v[0] = f2bf(x.x * s); v[1] = f2bf(x.y * s);
                v[2] = f2bf(x.z * s); v[3] = f2bf(x.w * s);
                v[4] = f2bf(y.x * s); v[5] = f2bf(y.y * s);
                v[6] = f2bf(y.z * s); v[7] = f2bf(y.w * s);
                int row = strow + h * 64;
                *(us8*)&ldst[bi][row * LP + (skq ^ sw) * 8] = v;
            }
        }
    };

    const unsigned short* RB0 = diag ? LA0 : LB0;
    const unsigned short* RB1 = diag ? LA1 : LB1;

    f32x4 accI[4][4], accT[4][4];
#pragma unroll
    for (int m = 0; m < 4; ++m)
#pragma unroll
        for (int n = 0; n < 4; ++n) {
            f32x4 z = { 0.f, 0.f, 0.f, 0.f };
            accI[m][n] = z; accT[m][n] = z;
        }

    STAGE_LOAD(0);
    for (int ks = 0; ks < DIM / GKC; ++ks) {
        __syncthreads();
        STAGE_WRITE();
        __syncthreads();
        if (ks + 1 < DIM / GKC) STAGE_LOAD(GKC * (ks + 1));

        bf16x8 aI[4], aT[4], bI[4], bT[4];
#pragma unroll
        for (int m = 0; m < 4; ++m) {
            int row = wr + m * 16 + (lane & 15);
            int off = row * LP + (((lane >> 4) ^ ((row >> 3) & 3))) * 8;
            aI[m] = *(const bf16x8*)&LA0[off];
            aT[m] = *(const bf16x8*)&LA1[off];
        }
#pragma unroll
        for (int n = 0; n < 4; ++n) {
            int row = wc + n * 16 + (lane & 15);
            int off = row * LP + (((lane >> 4) ^ ((row >> 3) & 3))) * 8;
            bI[n] = *(const bf16x8*)&RB0[off];
            bT[n] = *(const bf16x8*)&RB1[off];
        }
#pragma unroll
        for (int m = 0; m < 4; ++m)
#pragma unroll
            for (int n = 0; n < 4; ++n) {
                accI[m][n] = __builtin_amdgcn_mfma_f32_16x16x32_bf16(aI[m], bI[n], accI[m][n], 0, 0, 0);
                accT[m][n] = __builtin_amdgcn_mfma_f32_16x16x32_bf16(aT[m], bT[n], accT[m][n], 0, 0, 0);
            }
    }

    const int r4 = lane >> 4, cl = lane & 15;
    float wq[4], wp[4][4];
#pragma unroll
    for (int n = 0; n < 4; ++n) wq[n] = weights[bP + qc + wc + n * 16 + cl];
#pragma unroll
    for (int m = 0; m < 4; ++m)
#pragma unroll
        for (int r = 0; r < 4; ++r) wp[m][r] = weights[bP + pr + wr + m * 16 + r4 * 4 + r];
    float local = 0.f;
#pragma unroll
    for (int m = 0; m < 4; ++m)
#pragma unroll
        for (int n = 0; n < 4; ++n)
#pragma unroll
            for (int r = 0; r < 4; ++r) {
                float d = accI[m][n][r] - accT[m][n][r];
                local += wp[m][r] * wq[n] * d * d;
            }
    local *= factor;
    red[tid] = local; __syncthreads();
    for (int s = 128; s; s >>= 1) { if (tid < s) red[tid] += red[tid + s]; __syncthreads(); }
    if (tid == 0) grampart[wg] = red[0];
}

// ---------------------------------------------------------------- kernel 5
__global__ __launch_bounds__(256) void k_final(const float* __restrict__ simpart,
                                               const float* __restrict__ grampart,
                                               int ngram,
                                               float* __restrict__ out) {
    __shared__ float red[256];
    int t = threadIdx.x;
    float v = (t < BT) ? simpart[t] : 0.f;
    float g = 0.f;
    for (int i = t; i < ngram; i += 256) g += grampart[i];
    v += 10.f * g;
    red[t] = v; __syncthreads();
    for (int s = 128; s; s >>= 1) { if (t < s) red[t] += red[t + s]; __syncthreads(); }
    if (t == 0) out[0] = red[0] * (1.f / BT);
}

// ---------------------------------------------------------------- launch
extern "C" void kernel_launch(void* const* d_in, const int* in_sizes, int n_in,
                              void* d_out, int out_size, void* d_ws, size_t ws_size,
                              hipStream_t stream) {
    (void)in_sizes; (void)n_in; (void)out_size;
    const float* in = (const float*)d_in[0];
    const float* tg = (const float*)d_in[1];

    const size_t bfBytes   = (size_t)NROWS * DIM * 2;     // one bf16 matrix
    const size_t floatsOff = 2 * bfBytes;
    const size_t fCount    = 5 * (size_t)NROWS + (size_t)NWG_N * DIM
                           + (size_t)BT * DIM + DIM + BT + NGRAM;
    const size_t needed    = floatsOff + fCount * 4;
    const bool   pre       = ws_size >= needed;

    char* wsb = (char*)d_ws;
    unsigned short* in_n = nullptr;
    unsigned short* tg_n = nullptr;
    float* fbase;
    if (pre) {
        in_n  = (unsigned short*)wsb;
        tg_n  = (unsigned short*)(wsb + bfBytes);
        fbase = (float*)(wsb + floatsOff);
    } else {
        fbase = (float*)wsb;
    }
    float* inv_in  = fbase;
    float* inv_tg  = fbase + NROWS;
    float* ploss   = fbase + 2 * (size_t)NROWS;
    float* wraw    = fbase + 3 * (size_t)NROWS;
    float* weights = fbase + 4 * (size_t)NROWS;
    float* psum    = fbase + 5 * (size_t)NROWS;            // NWG_N*DIM (6.3 MB)
    float* bsum    = psum + (size_t)NWG_N * DIM;           // BT*DIM
    float* va      = bsum + (size_t)BT * DIM;              // DIM
    float* simpart = va + DIM;                             // BT
    float* grampart= simpart + BT;                         // NGRAM

    if (pre) {
        k_norms<1><<<NWG_N, 256, 0, stream>>>(in, tg, inv_in, inv_tg, ploss, in_n, tg_n, psum);
    } else {
        k_norms<0><<<NWG_N, 256, 0, stream>>>(in, tg, inv_in, inv_tg, ploss, nullptr, nullptr, psum);
    }
    k_bsum2<<<dim3(BT, 3), 256, 0, stream>>>(psum, bsum);
    k_gmean<<<3, 256, 0, stream>>>(bsum, va);
    k_wdots<<<NROWS / 16, 256, 0, stream>>>(tg, inv_tg, bsum, va, wraw);
    k_wfinal<<<BT, 256, 0, stream>>>(wraw, ploss, weights, simpart);
    if (pre) {
        k_gram<<<NGRAM, 256, 0, stream>>>(in_n, tg_n, weights, grampart);
        k_final<<<1, 256, 0, stream>>>(simpart, grampart, NGRAM, (float*)d_out);
    } else {
        k_gram_f32<<<192, 256, 0, stream>>>(in, tg, inv_in, inv_tg, weights, grampart);
        k_final<<<1, 256, 0, stream>>>(simpart, grampart, 192, (float*)d_out);
    }
}